// Round 2
// baseline (237.832 us; speedup 1.0000x reference)
//
#include <hip/hip_runtime.h>

typedef __bf16 bf16_t;
typedef bf16_t bf16x8 __attribute__((ext_vector_type(8)));
typedef float f32x4 __attribute__((ext_vector_type(4)));
typedef unsigned short u16x8 __attribute__((ext_vector_type(8)));
typedef unsigned short u16x4 __attribute__((ext_vector_type(4)));

#define CD 768
#define NT 196
#define NB 128
#define T2 392
#define MROWS (NB*NT)   // 25088

__device__ __forceinline__ unsigned short f2bf(float f){
  unsigned u = __float_as_uint(f);
  u += 0x7fffu + ((u >> 16) & 1u);
  return (unsigned short)(u >> 16);
}
__device__ __forceinline__ float bf2f(unsigned short h){
  return __uint_as_float(((unsigned)h) << 16);
}
__device__ __forceinline__ float wave_reduce(float v){
  #pragma unroll
  for (int o = 32; o > 0; o >>= 1) v += __shfl_down(v, o, 64);
  return v;
}
__device__ __forceinline__ void gload16(const unsigned short* g, unsigned short* l){
  __builtin_amdgcn_global_load_lds(
      (const __attribute__((address_space(1))) unsigned int*)g,
      (__attribute__((address_space(3))) unsigned int*)l, 16, 0, 0);
}

// Transpose W1/W2 into bf16 [n][k].
__global__ void prep_wt(const float* __restrict__ W1, const float* __restrict__ W2,
                        unsigned short* __restrict__ W1t, unsigned short* __restrict__ W2t){
  int id = blockIdx.x*256 + threadIdx.x;
  if (id >= CD*CD) return;
  int n = id / CD, k = id - n*CD;
  W1t[id] = f2bf(W1[k*CD + n]);
  W2t[id] = f2bf(W2[k*CD + n]);
}

// u3[k] = W3[k,:]@w5a ; u4s[j] = (W4[j,:]+W4[392+j,:])@w5b ; c = b3@w5a + b4@w5b + b5
__global__ void prep_u(const float* __restrict__ W3, const float* __restrict__ W4,
                       const float* __restrict__ W5, const float* __restrict__ b3,
                       const float* __restrict__ b4, const float* __restrict__ b5,
                       float* __restrict__ u3, float* __restrict__ u4s, float* __restrict__ cbuf){
  int wid = (blockIdx.x*blockDim.x + threadIdx.x) >> 6;
  int lane = threadIdx.x & 63;
  const float* w5a = W5;
  const float* w5b = W5 + CD;
  float s = 0.f;
  if (wid < CD){
    const float* row = W3 + (size_t)wid*CD;
    for (int k = lane; k < CD; k += 64) s += row[k]*w5a[k];
    s = wave_reduce(s);
    if (lane == 0) u3[wid] = s;
  } else if (wid < CD + T2){
    int j = wid - CD;
    const float* r0 = W4 + (size_t)j*784;
    const float* r1 = W4 + (size_t)(j+T2)*784;
    for (int e = lane; e < 784; e += 64) s += (r0[e]+r1[e])*w5b[e];
    s = wave_reduce(s);
    if (lane == 0) u4s[j] = s;
  } else if (wid == CD + T2){
    for (int k = lane; k < CD; k += 64) s += b3[k]*w5a[k];
    for (int e = lane; e < 784; e += 64) s += b4[e]*w5b[e];
    s = wave_reduce(s);
    if (lane == 0) cbuf[0] = s + b5[0];
  }
}

// fp32 -> bf16 streaming convert (8 elems/thread)
__global__ __launch_bounds__(256) void cvt_bf16(const float* __restrict__ src,
                                                unsigned short* __restrict__ dst){
  int id = blockIdx.x*256 + threadIdx.x;
  float4 a = ((const float4*)src)[id*2];
  float4 b = ((const float4*)src)[id*2+1];
  u16x8 o = { f2bf(a.x), f2bf(a.y), f2bf(a.z), f2bf(a.w),
              f2bf(b.x), f2bf(b.y), f2bf(b.z), f2bf(b.w) };
  ((u16x8*)dst)[id] = o;
}

// phi = relu((A@Bt^T + b)*g + be); A [M,768] bf16, Bt [768,768] bf16 [n][k].
// 128x128 tile, BK=64, global_load_lds staging, pre-swizzled source + swizzled ds_read.
__global__ __launch_bounds__(256) void phi_gemm(
    const unsigned short* __restrict__ A, const unsigned short* __restrict__ Bt,
    const float* __restrict__ bias, const float* __restrict__ gam,
    const float* __restrict__ bet, unsigned short* __restrict__ phi)
{
  __shared__ unsigned short As[128*64];
  __shared__ unsigned short Bs[128*64];

  const int tid  = threadIdx.x;
  const int lane = tid & 63;
  const int w    = tid >> 6;
  const int wr = w >> 1, wc = w & 1;

  // XCD-bijective swizzle: 1176 = 8*147, bn fastest within an XCD's chunk
  int orig = blockIdx.x;
  int swz  = (orig & 7)*147 + (orig >> 3);
  int bn = swz % 6;
  int bm = swz / 6;

  // staging: wave w covers rows w*32 + c*8 + lane/8, phys slot lane%8 (16B slots of a 128B row)
  const int srow  = lane >> 3;
  const int p     = lane & 7;
  const int gslot = (p - srow) & 7;          // source pre-swizzle (row&7 == lane>>3 here)
  const unsigned short* ag = A  + (size_t)(bm*128 + w*32 + srow)*CD + gslot*8;
  const unsigned short* bg = Bt + (size_t)(bn*128 + w*32 + srow)*CD + gslot*8;
  unsigned short* al = &As[(w*32)*64];
  unsigned short* bl = &Bs[(w*32)*64];

  f32x4 acc[4][4] = {};

  for (int kt = 0; kt < 12; ++kt){
    #pragma unroll
    for (int c = 0; c < 4; ++c){
      gload16(ag + (size_t)c*8*CD + kt*64, al + c*8*64);
      gload16(bg + (size_t)c*8*CD + kt*64, bl + c*8*64);
    }
    __syncthreads();   // drains vmcnt -> staged data visible
    #pragma unroll
    for (int kk = 0; kk < 2; ++kk){
      const int phys = (kk*4 + (lane >> 4) + (lane & 7)) & 7;  // (q + row&7)&7, row&7==lane&7
      bf16x8 af[4], bq[4];
      #pragma unroll
      for (int mi = 0; mi < 4; ++mi){
        int r = wr*64 + mi*16 + (lane & 15);
        af[mi] = *(const bf16x8*)(&As[r*64 + phys*8]);
      }
      #pragma unroll
      for (int ni = 0; ni < 4; ++ni){
        int cr = wc*64 + ni*16 + (lane & 15);
        bq[ni] = *(const bf16x8*)(&Bs[cr*64 + phys*8]);
      }
      #pragma unroll
      for (int mi = 0; mi < 4; ++mi)
        #pragma unroll
        for (int ni = 0; ni < 4; ++ni)
          acc[mi][ni] = __builtin_amdgcn_mfma_f32_16x16x32_bf16(af[mi], bq[ni], acc[mi][ni], 0, 0, 0);
    }
    __syncthreads();   // all reads done before next stage overwrites
  }

  #pragma unroll
  for (int ni = 0; ni < 4; ++ni){
    int col = bn*128 + wc*64 + ni*16 + (lane & 15);
    float bi = bias[col], ga = gam[col], be = bet[col];
    #pragma unroll
    for (int mi = 0; mi < 4; ++mi){
      int r0 = bm*128 + wr*64 + mi*16 + ((lane >> 4) << 2);
      #pragma unroll
      for (int j = 0; j < 4; ++j){
        float v = (acc[mi][ni][j] + bi)*ga + be;
        v = fmaxf(v, 0.f);
        phi[(size_t)(r0 + j)*CD + col] = f2bf(v);
      }
    }
  }
}

// t[b,d] = u3[d] + sum_i u4s[i]*phiX[b,i,d] + sum_i u4s[196+i]*phiY[b,i,d]
__global__ __launch_bounds__(256) void comp_t(const unsigned short* __restrict__ phiX,
                       const unsigned short* __restrict__ phiY,
                       const float* __restrict__ u3, const float* __restrict__ u4s,
                       float* __restrict__ t){
  __shared__ float su[T2];
  int b = blockIdx.x;
  int d = blockIdx.y*256 + threadIdx.x;
  for (int j = threadIdx.x; j < T2; j += 256) su[j] = u4s[j];
  __syncthreads();
  const unsigned short* px = phiX + (size_t)b*NT*CD + d;
  const unsigned short* py = phiY + (size_t)b*NT*CD + d;
  float s = 0.f;
  #pragma unroll 4
  for (int i = 0; i < NT; ++i) s += su[i]*bf2f(px[(size_t)i*CD]);
  #pragma unroll 4
  for (int i = 0; i < NT; ++i) s += su[NT+i]*bf2f(py[(size_t)i*CD]);
  t[b*CD + d] = u3[d] + s;
}

// Wf[s*25088 + local] = phi_row . t[b,:] + c   (one wave per row)
__global__ __launch_bounds__(256) void comp_w(const unsigned short* __restrict__ phiX,
                       const unsigned short* __restrict__ phiY,
                       const float* __restrict__ t, const float* __restrict__ cbuf,
                       float* __restrict__ Wf){
  int gw = (blockIdx.x*256 + threadIdx.x) >> 6;   // 0..50175
  int lane = threadIdx.x & 63;
  int s1 = gw >= MROWS;
  int local = gw - s1*MROWS;
  int b = local / NT;
  const unsigned short* p = (s1 ? phiY : phiX) + (size_t)local*CD;
  const float* tb = t + b*CD;
  float s = 0.f;
  #pragma unroll
  for (int it = 0; it < 3; ++it){
    int k = it*256 + lane*4;
    u16x4 u = *(const u16x4*)(p + k);
    float4 tv = *(const float4*)(tb + k);
    s += bf2f(u.x)*tv.x + bf2f(u.y)*tv.y + bf2f(u.z)*tv.z + bf2f(u.w)*tv.w;
  }
  s = wave_reduce(s);
  if (lane == 0) Wf[gw] = s + cbuf[0];
}

// out = x*Wx + y*Wy (float4 per thread)
__global__ __launch_bounds__(256) void comp_out(const float* __restrict__ x,
                         const float* __restrict__ y, const float* __restrict__ Wf,
                         float* __restrict__ out){
  int id = blockIdx.x*256 + threadIdx.x;     // one float4
  int tokv = id / 192;                       // b*196 + i
  float wx = Wf[tokv];
  float wy = Wf[MROWS + tokv];
  float4 xv = ((const float4*)x)[id];
  float4 yv = ((const float4*)y)[id];
  float4 o;
  o.x = xv.x*wx + yv.x*wy;
  o.y = xv.y*wx + yv.y*wy;
  o.z = xv.z*wx + yv.z*wy;
  o.w = xv.w*wx + yv.w*wy;
  ((float4*)out)[id] = o;
}

extern "C" void kernel_launch(void* const* d_in, const int* in_sizes, int n_in,
                              void* d_out, int out_size, void* d_ws, size_t ws_size,
                              hipStream_t stream){
  const float* x  = (const float*)d_in[0];
  const float* y  = (const float*)d_in[1];
  const float* W1 = (const float*)d_in[2];
  const float* b1 = (const float*)d_in[3];
  const float* g1 = (const float*)d_in[4];
  const float* be1= (const float*)d_in[5];
  const float* W2 = (const float*)d_in[6];
  const float* b2 = (const float*)d_in[7];
  const float* g2 = (const float*)d_in[8];
  const float* be2= (const float*)d_in[9];
  const float* W3 = (const float*)d_in[10];
  const float* b3 = (const float*)d_in[11];
  const float* W4 = (const float*)d_in[12];
  const float* b4 = (const float*)d_in[13];
  const float* W5 = (const float*)d_in[14];
  const float* b5 = (const float*)d_in[15];
  float* out = (float*)d_out;

  unsigned short* W1t = (unsigned short*)d_ws;          // 768*768 bf16
  unsigned short* W2t = W1t + CD*CD;
  unsigned short* xybf = W2t + CD*CD;                   // 25088*768 bf16 (temp, reused)
  unsigned short* phiX = xybf + (size_t)MROWS*CD;       // 25088*768 bf16
  unsigned short* phiY = phiX + (size_t)MROWS*CD;       // 25088*768 bf16
  float* u3   = (float*)(phiY + (size_t)MROWS*CD);      // 768
  float* u4s  = u3 + CD;                                // 392
  float* cbuf = u4s + T2;                               // 1 (+pad)
  float* t    = cbuf + 4;                               // 128*768
  float* Wf   = t + NB*CD;                              // 2*25088

  prep_wt<<<(CD*CD + 255)/256, 256, 0, stream>>>(W1, W2, W1t, W2t);
  prep_u<<<(CD + T2 + 4)/4, 256, 0, stream>>>(W3, W4, W5, b3, b4, b5, u3, u4s, cbuf);

  const int nCvt = (MROWS*CD/8)/256;     // 9408
  cvt_bf16<<<nCvt, 256, 0, stream>>>(x, xybf);
  phi_gemm<<<1176, 256, 0, stream>>>(xybf, W1t, b1, g1, be1, phiX);
  cvt_bf16<<<nCvt, 256, 0, stream>>>(y, xybf);
  phi_gemm<<<1176, 256, 0, stream>>>(xybf, W2t, b2, g2, be2, phiY);

  comp_t<<<dim3(NB, 3), 256, 0, stream>>>(phiX, phiY, u3, u4s, t);
  comp_w<<<(2*MROWS)/4, 256, 0, stream>>>(phiX, phiY, t, cbuf, Wf);
  comp_out<<<(MROWS*CD/4)/256, 256, 0, stream>>>(x, y, Wf, out);
}

// Round 3
// 232.072 us; speedup vs baseline: 1.0248x; 1.0248x over previous
//
#include <hip/hip_runtime.h>

typedef __bf16 bf16_t;
typedef bf16_t bf16x8 __attribute__((ext_vector_type(8)));
typedef float f32x4 __attribute__((ext_vector_type(4)));
typedef unsigned short u16x8 __attribute__((ext_vector_type(8)));
typedef unsigned short u16x4 __attribute__((ext_vector_type(4)));

#define CD 768
#define NT 196
#define NB 128
#define T2 392
#define MROWS (NB*NT)   // 25088

__device__ __forceinline__ unsigned short f2bf(float f){
  unsigned u = __float_as_uint(f);
  u += 0x7fffu + ((u >> 16) & 1u);
  return (unsigned short)(u >> 16);
}
__device__ __forceinline__ float bf2f(unsigned short h){
  return __uint_as_float(((unsigned)h) << 16);
}
__device__ __forceinline__ float wave_reduce(float v){
  #pragma unroll
  for (int o = 32; o > 0; o >>= 1) v += __shfl_down(v, o, 64);
  return v;
}
__device__ __forceinline__ void gload16(const unsigned short* g, unsigned short* l){
  __builtin_amdgcn_global_load_lds(
      (const __attribute__((address_space(1))) unsigned int*)g,
      (__attribute__((address_space(3))) unsigned int*)l, 16, 0, 0);
}

// LDS-tiled transpose W1/W2 -> bf16 [n][k]; reads and writes coalesced.
__global__ __launch_bounds__(256) void prep_wt(const float* __restrict__ W1,
                        const float* __restrict__ W2,
                        unsigned short* __restrict__ W1t, unsigned short* __restrict__ W2t){
  __shared__ float tile[64][65];
  const float* src = blockIdx.z ? W2 : W1;
  unsigned short* dst = blockIdx.z ? W2t : W1t;
  int k0 = blockIdx.x*64, n0 = blockIdx.y*64;
  int tid = threadIdx.x;
  #pragma unroll
  for (int e = 0; e < 16; ++e){
    int idx = e*256 + tid;
    int r = idx >> 6, c = idx & 63;
    tile[r][c] = src[(size_t)(k0+r)*CD + n0 + c];
  }
  __syncthreads();
  #pragma unroll
  for (int e = 0; e < 16; ++e){
    int idx = e*256 + tid;
    int nr = idx >> 6, kc = idx & 63;
    dst[(size_t)(n0+nr)*CD + k0 + kc] = f2bf(tile[kc][nr]);
  }
}

// u3[k] = W3[k,:]@w5a ; u4s[j] = (W4[j,:]+W4[392+j,:])@w5b ; c = b3@w5a + b4@w5b + b5
__global__ void prep_u(const float* __restrict__ W3, const float* __restrict__ W4,
                       const float* __restrict__ W5, const float* __restrict__ b3,
                       const float* __restrict__ b4, const float* __restrict__ b5,
                       float* __restrict__ u3, float* __restrict__ u4s, float* __restrict__ cbuf){
  int wid = (blockIdx.x*blockDim.x + threadIdx.x) >> 6;
  int lane = threadIdx.x & 63;
  const float* w5a = W5;
  const float* w5b = W5 + CD;
  float s = 0.f;
  if (wid < CD){
    const float* row = W3 + (size_t)wid*CD;
    for (int k = lane; k < CD; k += 64) s += row[k]*w5a[k];
    s = wave_reduce(s);
    if (lane == 0) u3[wid] = s;
  } else if (wid < CD + T2){
    int j = wid - CD;
    const float* r0 = W4 + (size_t)j*784;
    const float* r1 = W4 + (size_t)(j+T2)*784;
    for (int e = lane; e < 784; e += 64) s += (r0[e]+r1[e])*w5b[e];
    s = wave_reduce(s);
    if (lane == 0) u4s[j] = s;
  } else if (wid == CD + T2){
    for (int k = lane; k < CD; k += 64) s += b3[k]*w5a[k];
    for (int e = lane; e < 784; e += 64) s += b4[e]*w5b[e];
    s = wave_reduce(s);
    if (lane == 0) cbuf[0] = s + b5[0];
  }
}

// t[b,d] := u3[d]  (plus one pad row of zeros at b=128 for straddle atomics)
__global__ void init_t(const float* __restrict__ u3, float* __restrict__ t){
  int i = blockIdx.x*256 + threadIdx.x;
  if (i < (NB+1)*CD) t[i] = (i < NB*CD) ? u3[i % CD] : 0.f;
}

// fp32 -> bf16 streaming convert (8 elems/thread)
__global__ __launch_bounds__(256) void cvt_bf16(const float* __restrict__ src,
                                                unsigned short* __restrict__ dst){
  int id = blockIdx.x*256 + threadIdx.x;
  float4 a = ((const float4*)src)[id*2];
  float4 b = ((const float4*)src)[id*2+1];
  u16x8 o = { f2bf(a.x), f2bf(a.y), f2bf(a.z), f2bf(a.w),
              f2bf(b.x), f2bf(b.y), f2bf(b.z), f2bf(b.w) };
  ((u16x8*)dst)[id] = o;
}

// phi = relu((A@Bt^T + b)*g + be); fused t-accumulation (weighted column sums).
// 128x128 tile, BK=32 double-buffered, counted vmcnt(4), raw barriers, setprio.
__global__ __launch_bounds__(256) void phi_gemm(
    const unsigned short* __restrict__ A, const unsigned short* __restrict__ Bt,
    const float* __restrict__ bias, const float* __restrict__ gam,
    const float* __restrict__ bet, const float* __restrict__ u4c,
    unsigned short* __restrict__ phi, float* __restrict__ t)
{
  __shared__ unsigned short As[2][4096];   // [dbuf][128 rows x 32 k]
  __shared__ unsigned short Bs[2][4096];

  const int tid  = threadIdx.x;
  const int lane = tid & 63;
  const int w    = tid >> 6;
  const int wr = w >> 1, wc = w & 1;

  // XCD-bijective chunked swizzle (grid % 8 == 0)
  const int chunk = gridDim.x >> 3;
  int orig = blockIdx.x;
  int swz  = (orig & 7)*chunk + (orig >> 3);
  int bn = swz % 6;
  int bm = swz / 6;

  // staging: slot s = r*256+tid covers (row=s>>2, q=tid&3); source slot g = q ^ ((row>>1)&3)
  const int row0 = tid >> 2;
  const int q    = tid & 3;
  const int g0   = q ^ ((row0 >> 1) & 3);      // same for row0+64
  const unsigned short* a0 = A  + (size_t)(bm*128 + row0     )*CD + g0*8;
  const unsigned short* a1 = A  + (size_t)(bm*128 + row0 + 64)*CD + g0*8;
  const unsigned short* b0 = Bt + (size_t)(bn*128 + row0     )*CD + g0*8;
  const unsigned short* b1 = Bt + (size_t)(bn*128 + row0 + 64)*CD + g0*8;
  const int l0 = tid*8, l1 = 2048 + tid*8;

  // fragment read offsets: row r, phys slot = f ^ ((r&7)>>1)
  const int fr = lane & 15, f = lane >> 4;
  const int qp = f ^ ((fr & 7) >> 1);
  int aoff[4], boff[4];
  #pragma unroll
  for (int mi = 0; mi < 4; ++mi) aoff[mi] = (wr*64 + mi*16 + fr)*32 + qp*8;
  #pragma unroll
  for (int ni = 0; ni < 4; ++ni) boff[ni] = (wc*64 + ni*16 + fr)*32 + qp*8;

  f32x4 acc[4][4] = {};

#define STAGE(D, KT) { int ko = (KT)*32;                \
    gload16(a0 + ko, &As[D][l0]);                       \
    gload16(a1 + ko, &As[D][l1]);                       \
    gload16(b0 + ko, &Bs[D][l0]);                       \
    gload16(b1 + ko, &Bs[D][l1]); }

#define STEP(D, KT, LAST) {                                              \
    if (LAST) { asm volatile("s_waitcnt vmcnt(0)" ::: "memory"); }       \
    else      { asm volatile("s_waitcnt vmcnt(4)" ::: "memory"); }       \
    __builtin_amdgcn_s_barrier();                                        \
    bf16x8 af[4], bq[4];                                                 \
    _Pragma("unroll")                                                    \
    for (int mi = 0; mi < 4; ++mi) af[mi] = *(const bf16x8*)(&As[D][aoff[mi]]); \
    _Pragma("unroll")                                                    \
    for (int ni = 0; ni < 4; ++ni) bq[ni] = *(const bf16x8*)(&Bs[D][boff[ni]]); \
    __builtin_amdgcn_s_setprio(1);                                       \
    _Pragma("unroll")                                                    \
    for (int mi = 0; mi < 4; ++mi)                                       \
      _Pragma("unroll")                                                  \
      for (int ni = 0; ni < 4; ++ni)                                     \
        acc[mi][ni] = __builtin_amdgcn_mfma_f32_16x16x32_bf16(af[mi], bq[ni], acc[mi][ni], 0, 0, 0); \
    __builtin_amdgcn_s_setprio(0);                                       \
    __builtin_amdgcn_s_barrier();                                        \
    if ((KT) < 22) STAGE(D, (KT)+2); }

  STAGE(0, 0)
  STAGE(1, 1)
  #pragma unroll 1
  for (int kp = 0; kp < 11; ++kp){
    STEP(0, 2*kp,   false)
    STEP(1, 2*kp+1, false)
  }
  STEP(0, 22, false)
  STEP(1, 23, true)
#undef STEP
#undef STAGE

  // epilogue: BN-affine + ReLU, store bf16 phi; accumulate t[b,col] += u4c[tok]*v
  const int b_base = (bm*128) / NT;
  #pragma unroll
  for (int ni = 0; ni < 4; ++ni){
    int col = bn*128 + wc*64 + ni*16 + fr;
    float bi = bias[col], ga = gam[col], be = bet[col];
    float c0 = 0.f, c1 = 0.f;
    #pragma unroll
    for (int mi = 0; mi < 4; ++mi){
      int r0 = bm*128 + wr*64 + mi*16 + f*4;
      #pragma unroll
      for (int j = 0; j < 4; ++j){
        int r = r0 + j;
        float v = fmaxf((acc[mi][ni][j] + bi)*ga + be, 0.f);
        phi[(size_t)r*CD + col] = f2bf(v);
        int b = r / NT;
        int tok = r - b*NT;
        float pv = u4c[tok]*v;
        if (b == b_base) c0 += pv; else c1 += pv;
      }
    }
    c0 += __shfl_xor(c0, 16, 64); c0 += __shfl_xor(c0, 32, 64);
    c1 += __shfl_xor(c1, 16, 64); c1 += __shfl_xor(c1, 32, 64);
    if (lane < 16){
      atomicAdd(&t[(size_t)b_base*CD + col], c0);
      atomicAdd(&t[(size_t)(b_base+1)*CD + col], c1);  // b_base+1 may be pad row 128
    }
  }
}

// Wf[gw] = phi_row(gw) . t[b,:] + c   (one wave per row; gw spans X then Y)
__global__ __launch_bounds__(256) void comp_w(const unsigned short* __restrict__ phi,
                       const float* __restrict__ t, const float* __restrict__ cbuf,
                       float* __restrict__ Wf){
  int gw = (blockIdx.x*256 + threadIdx.x) >> 6;   // 0..50175
  int lane = threadIdx.x & 63;
  int s1 = gw >= MROWS;
  int local = gw - s1*MROWS;
  int b = local / NT;
  const unsigned short* p = phi + (size_t)gw*CD;
  const float* tb = t + (size_t)b*CD;
  float s = 0.f;
  #pragma unroll
  for (int it = 0; it < 3; ++it){
    int k = it*256 + lane*4;
    u16x4 u = *(const u16x4*)(p + k);
    float4 tv = *(const float4*)(tb + k);
    s += bf2f(u.x)*tv.x + bf2f(u.y)*tv.y + bf2f(u.z)*tv.z + bf2f(u.w)*tv.w;
  }
  s = wave_reduce(s);
  if (lane == 0) Wf[gw] = s + cbuf[0];
}

// out = x*Wx + y*Wy (float4 per thread)
__global__ __launch_bounds__(256) void comp_out(const float* __restrict__ x,
                         const float* __restrict__ y, const float* __restrict__ Wf,
                         float* __restrict__ out){
  int id = blockIdx.x*256 + threadIdx.x;     // one float4
  int tokv = id / 192;                       // b*196 + i
  float wx = Wf[tokv];
  float wy = Wf[MROWS + tokv];
  float4 xv = ((const float4*)x)[id];
  float4 yv = ((const float4*)y)[id];
  float4 o;
  o.x = xv.x*wx + yv.x*wy;
  o.y = xv.y*wx + yv.y*wy;
  o.z = xv.z*wx + yv.z*wy;
  o.w = xv.w*wx + yv.w*wy;
  ((float4*)out)[id] = o;
}

extern "C" void kernel_launch(void* const* d_in, const int* in_sizes, int n_in,
                              void* d_out, int out_size, void* d_ws, size_t ws_size,
                              hipStream_t stream){
  const float* x  = (const float*)d_in[0];
  const float* y  = (const float*)d_in[1];
  const float* W1 = (const float*)d_in[2];
  const float* b1 = (const float*)d_in[3];
  const float* g1 = (const float*)d_in[4];
  const float* be1= (const float*)d_in[5];
  const float* W2 = (const float*)d_in[6];
  const float* b2 = (const float*)d_in[7];
  const float* g2 = (const float*)d_in[8];
  const float* be2= (const float*)d_in[9];
  const float* W3 = (const float*)d_in[10];
  const float* b3 = (const float*)d_in[11];
  const float* W4 = (const float*)d_in[12];
  const float* b4 = (const float*)d_in[13];
  const float* W5 = (const float*)d_in[14];
  const float* b5 = (const float*)d_in[15];
  float* out = (float*)d_out;

  unsigned short* W1t = (unsigned short*)d_ws;          // 768*768 bf16
  unsigned short* W2t = W1t + CD*CD;
  unsigned short* xybf = W2t + CD*CD;                   // 25088*768 bf16 (reused for x, then y)
  unsigned short* phi  = xybf + (size_t)MROWS*CD;       // 2*25088*768 bf16 (X rows then Y rows)
  float* u3   = (float*)(phi + (size_t)2*MROWS*CD);     // 768
  float* u4s  = u3 + CD;                                // 392
  float* cbuf = u4s + T2;                               // 1 (+pad)
  float* t    = cbuf + 4;                               // (128+1)*768
  float* Wf   = t + (NB+1)*CD;                          // 2*25088

  prep_wt<<<dim3(12,12,2), 256, 0, stream>>>(W1, W2, W1t, W2t);
  prep_u<<<(CD + T2 + 4)/4, 256, 0, stream>>>(W3, W4, W5, b3, b4, b5, u3, u4s, cbuf);
  init_t<<<((NB+1)*CD + 255)/256, 256, 0, stream>>>(u3, t);

  const int nCvt = (MROWS*CD/8)/256;     // 9408
  cvt_bf16<<<nCvt, 256, 0, stream>>>(x, xybf);
  phi_gemm<<<1176, 256, 0, stream>>>(xybf, W1t, b1, g1, be1, u4s,      phi,               t);
  cvt_bf16<<<nCvt, 256, 0, stream>>>(y, xybf);
  phi_gemm<<<1176, 256, 0, stream>>>(xybf, W2t, b2, g2, be2, u4s + NT, phi + (size_t)MROWS*CD, t);

  comp_w<<<(2*MROWS)/4, 256, 0, stream>>>(phi, t, cbuf, Wf);
  comp_out<<<(MROWS*CD/4)/256, 256, 0, stream>>>(x, y, Wf, out);
}

// Round 4
// 215.554 us; speedup vs baseline: 1.1034x; 1.0766x over previous
//
#include <hip/hip_runtime.h>

typedef __bf16 bf16_t;
typedef bf16_t bf16x8 __attribute__((ext_vector_type(8)));
typedef float f32x4 __attribute__((ext_vector_type(4)));
typedef unsigned short u16x8 __attribute__((ext_vector_type(8)));
typedef unsigned short u16x4 __attribute__((ext_vector_type(4)));

#define CD 768
#define NT 196
#define NB 128
#define T2 392
#define MROWS (NB*NT)   // 25088

__device__ __forceinline__ unsigned short f2bf(float f){
  unsigned u = __float_as_uint(f);
  u += 0x7fffu + ((u >> 16) & 1u);
  return (unsigned short)(u >> 16);
}
__device__ __forceinline__ float bf2f(unsigned short h){
  return __uint_as_float(((unsigned)h) << 16);
}
__device__ __forceinline__ float wave_reduce(float v){
  #pragma unroll
  for (int o = 32; o > 0; o >>= 1) v += __shfl_down(v, o, 64);
  return v;
}
__device__ __forceinline__ void gload16(const unsigned short* g, unsigned short* l){
  __builtin_amdgcn_global_load_lds(
      (const __attribute__((address_space(1))) unsigned int*)g,
      (__attribute__((address_space(3))) unsigned int*)l, 16, 0, 0);
}

// LDS-tiled transpose W1/W2 -> bf16 [n][k]; reads and writes coalesced.
__global__ __launch_bounds__(256) void prep_wt(const float* __restrict__ W1,
                        const float* __restrict__ W2,
                        unsigned short* __restrict__ W1t, unsigned short* __restrict__ W2t){
  __shared__ float tile[64][65];
  const float* src = blockIdx.z ? W2 : W1;
  unsigned short* dst = blockIdx.z ? W2t : W1t;
  int k0 = blockIdx.x*64, n0 = blockIdx.y*64;
  int tid = threadIdx.x;
  #pragma unroll
  for (int e = 0; e < 16; ++e){
    int idx = e*256 + tid;
    int r = idx >> 6, c = idx & 63;
    tile[r][c] = src[(size_t)(k0+r)*CD + n0 + c];
  }
  __syncthreads();
  #pragma unroll
  for (int e = 0; e < 16; ++e){
    int idx = e*256 + tid;
    int nr = idx >> 6, kc = idx & 63;
    dst[(size_t)(n0+nr)*CD + k0 + kc] = f2bf(tile[kc][nr]);
  }
}

// u3[k] = W3[k,:]@w5a ; u4s[j] = (W4[j,:]+W4[392+j,:])@w5b ; c = b3@w5a + b4@w5b + b5
__global__ void prep_u(const float* __restrict__ W3, const float* __restrict__ W4,
                       const float* __restrict__ W5, const float* __restrict__ b3,
                       const float* __restrict__ b4, const float* __restrict__ b5,
                       float* __restrict__ u3, float* __restrict__ u4s, float* __restrict__ cbuf){
  int wid = (blockIdx.x*blockDim.x + threadIdx.x) >> 6;
  int lane = threadIdx.x & 63;
  const float* w5a = W5;
  const float* w5b = W5 + CD;
  float s = 0.f;
  if (wid < CD){
    const float* row = W3 + (size_t)wid*CD;
    for (int k = lane; k < CD; k += 64) s += row[k]*w5a[k];
    s = wave_reduce(s);
    if (lane == 0) u3[wid] = s;
  } else if (wid < CD + T2){
    int j = wid - CD;
    const float* r0 = W4 + (size_t)j*784;
    const float* r1 = W4 + (size_t)(j+T2)*784;
    for (int e = lane; e < 784; e += 64) s += (r0[e]+r1[e])*w5b[e];
    s = wave_reduce(s);
    if (lane == 0) u4s[j] = s;
  } else if (wid == CD + T2){
    for (int k = lane; k < CD; k += 64) s += b3[k]*w5a[k];
    for (int e = lane; e < 784; e += 64) s += b4[e]*w5b[e];
    s = wave_reduce(s);
    if (lane == 0) cbuf[0] = s + b5[0];
  }
}

// t[b,d] := u3[d]  (plus one pad row of zeros at b=128 for straddle atomics)
__global__ void init_t(const float* __restrict__ u3, float* __restrict__ t){
  int i = blockIdx.x*256 + threadIdx.x;
  if (i < (NB+1)*CD) t[i] = (i < NB*CD) ? u3[i % CD] : 0.f;
}

// fp32 -> bf16: converts x then y into one contiguous dst (xbf | ybf), grid-stride.
__global__ __launch_bounds__(256) void cvt2(const float* __restrict__ x,
                                            const float* __restrict__ y,
                                            unsigned short* __restrict__ dst){
  const int nv = MROWS*CD/8;   // vec8 count per stream
  for (int id = blockIdx.x*256 + threadIdx.x; id < 2*nv; id += gridDim.x*256){
    const float* s = (id < nv) ? x : y;
    int i = (id < nv) ? id : id - nv;
    float4 a = ((const float4*)s)[i*2];
    float4 b = ((const float4*)s)[i*2+1];
    u16x8 o = { f2bf(a.x), f2bf(a.y), f2bf(a.z), f2bf(a.w),
                f2bf(b.x), f2bf(b.y), f2bf(b.z), f2bf(b.w) };
    ((u16x8*)dst)[id] = o;
  }
}

// phi = relu((A@Bt^T + b)*g + be); fused t-accumulation.
// 128x128 tile, BK=64 DOUBLE-buffered, verified 2-phase schedule:
//   STAGE next-tile loads FIRST, then ds_read+MFMA current, then one sync per tile.
__global__ __launch_bounds__(256, 2) void phi_gemm(
    const unsigned short* __restrict__ A, const unsigned short* __restrict__ Bt,
    const float* __restrict__ bias, const float* __restrict__ gam,
    const float* __restrict__ bet, const float* __restrict__ u4c,
    unsigned short* __restrict__ phi, float* __restrict__ t)
{
  __shared__ unsigned short As[2][128*64];
  __shared__ unsigned short Bs[2][128*64];

  const int tid  = threadIdx.x;
  const int lane = tid & 63;
  const int w    = tid >> 6;
  const int wr = w >> 1, wc = w & 1;

  // XCD-bijective swizzle (1176 = 8*147), bn-fastest within an XCD chunk
  int orig = blockIdx.x;
  int swz  = (orig & 7)*147 + (orig >> 3);
  int bn = swz % 6;
  int bm = swz / 6;

  // staging (R2-verified, 0 conflicts): wave w covers rows w*32+c*8+srow;
  // phys 16B-slot p holds global slot g=(p-row)&7  (additive mod-8 swizzle)
  const int srow = lane >> 3;
  const int p    = lane & 7;
  const int g0   = (p - srow) & 7;
  const unsigned short* a0 = A  + (size_t)(bm*128 + w*32 + srow)*CD + g0*8;
  const unsigned short* b0 = Bt + (size_t)(bn*128 + w*32 + srow)*CD + g0*8;
  unsigned short* al0 = &As[0][w*2048]; unsigned short* bl0 = &Bs[0][w*2048];
  unsigned short* al1 = &As[1][w*2048]; unsigned short* bl1 = &Bs[1][w*2048];

  const int fr = lane & 15, f = lane >> 4, r7 = lane & 7;
  f32x4 acc[4][4] = {};

#define STAGE(AL, BL, KT) { const int ko = (KT)*64;         \
    _Pragma("unroll")                                       \
    for (int c = 0; c < 4; ++c){                            \
      gload16(a0 + (size_t)c*8*CD + ko, AL + c*512);        \
      gload16(b0 + (size_t)c*8*CD + ko, BL + c*512); } }

#define COMPUTE(D) {                                                     \
    _Pragma("unroll")                                                    \
    for (int kk = 0; kk < 2; ++kk){                                      \
      bf16x8 af[4], bq[4];                                               \
      _Pragma("unroll")                                                  \
      for (int mi = 0; mi < 4; ++mi){ int rr = wr*64 + mi*16 + fr;       \
        af[mi] = *(const bf16x8*)(&As[D][rr*64 + (((kk*4+f)+r7)&7)*8]); }\
      _Pragma("unroll")                                                  \
      for (int ni = 0; ni < 4; ++ni){ int cc = wc*64 + ni*16 + fr;       \
        bq[ni] = *(const bf16x8*)(&Bs[D][cc*64 + (((kk*4+f)+r7)&7)*8]); }\
      _Pragma("unroll")                                                  \
      for (int mi = 0; mi < 4; ++mi)                                     \
        _Pragma("unroll")                                                \
        for (int ni = 0; ni < 4; ++ni)                                   \
          acc[mi][ni] = __builtin_amdgcn_mfma_f32_16x16x32_bf16(af[mi], bq[ni], acc[mi][ni], 0, 0, 0); } }

  STAGE(al0, bl0, 0)
  __syncthreads();
  #pragma unroll 1
  for (int kp = 0; kp < 5; ++kp){
    STAGE(al1, bl1, 2*kp+1)     // prefetch next tile: full compute phase to fly
    COMPUTE(0)
    __syncthreads();            // vmcnt(0)+lgkmcnt(0)+barrier: one drain per tile
    STAGE(al0, bl0, 2*kp+2)
    COMPUTE(1)
    __syncthreads();
  }
  STAGE(al1, bl1, 11)
  COMPUTE(0)
  __syncthreads();
  COMPUTE(1)
#undef COMPUTE
#undef STAGE

  // epilogue: BN-affine + ReLU, store bf16 phi; accumulate t[b,col] += u4c[tok]*v
  const int b_base = (bm*128) / NT;
  #pragma unroll
  for (int ni = 0; ni < 4; ++ni){
    int col = bn*128 + wc*64 + ni*16 + fr;
    float bi = bias[col], ga = gam[col], be = bet[col];
    float c0 = 0.f, c1 = 0.f;
    #pragma unroll
    for (int mi = 0; mi < 4; ++mi){
      int r0 = bm*128 + wr*64 + mi*16 + f*4;
      #pragma unroll
      for (int j = 0; j < 4; ++j){
        int r = r0 + j;
        float v = fmaxf((acc[mi][ni][j] + bi)*ga + be, 0.f);
        phi[(size_t)r*CD + col] = f2bf(v);
        int b = r / NT;
        int tok = r - b*NT;
        float pv = u4c[tok]*v;
        if (b == b_base) c0 += pv; else c1 += pv;
      }
    }
    c0 += __shfl_xor(c0, 16, 64); c0 += __shfl_xor(c0, 32, 64);
    c1 += __shfl_xor(c1, 16, 64); c1 += __shfl_xor(c1, 32, 64);
    if (lane < 16){
      atomicAdd(&t[(size_t)b_base*CD + col], c0);
      atomicAdd(&t[(size_t)(b_base+1)*CD + col], c1);  // b_base+1 may be pad row
    }
  }
}

// Fused: wx = phiX_row.t[b]+c, wy = phiY_row.t[b]+c, out_row = x_row*wx + y_row*wy.
// One wave per token.
__global__ __launch_bounds__(256) void comp_wout(
    const unsigned short* __restrict__ phiX, const unsigned short* __restrict__ phiY,
    const float* __restrict__ t, const float* __restrict__ cbuf,
    const float* __restrict__ x, const float* __restrict__ y, float* __restrict__ out)
{
  int gw   = (blockIdx.x*256 + threadIdx.x) >> 6;  // token 0..25087
  int lane = threadIdx.x & 63;
  int b = gw / NT;
  const unsigned short* px = phiX + (size_t)gw*CD;
  const unsigned short* py = phiY + (size_t)gw*CD;
  const float* tb = t + (size_t)b*CD;
  float s1 = 0.f, s2 = 0.f;
  #pragma unroll
  for (int it = 0; it < 3; ++it){
    int k = it*256 + lane*4;
    float4 tv = *(const float4*)(tb + k);
    u16x4 ux = *(const u16x4*)(px + k);
    u16x4 uy = *(const u16x4*)(py + k);
    s1 += bf2f(ux.x)*tv.x + bf2f(ux.y)*tv.y + bf2f(ux.z)*tv.z + bf2f(ux.w)*tv.w;
    s2 += bf2f(uy.x)*tv.x + bf2f(uy.y)*tv.y + bf2f(uy.z)*tv.z + bf2f(uy.w)*tv.w;
  }
  s1 = wave_reduce(s1);
  s2 = wave_reduce(s2);
  float c = cbuf[0];
  float wx = __shfl(s1, 0, 64) + c;
  float wy = __shfl(s2, 0, 64) + c;
  const float* xr = x + (size_t)gw*CD;
  const float* yr = y + (size_t)gw*CD;
  float* orow = out + (size_t)gw*CD;
  #pragma unroll
  for (int it = 0; it < 3; ++it){
    int k = it*256 + lane*4;
    float4 xv = *(const float4*)(xr + k);
    float4 yv = *(const float4*)(yr + k);
    float4 o;
    o.x = xv.x*wx + yv.x*wy;
    o.y = xv.y*wx + yv.y*wy;
    o.z = xv.z*wx + yv.z*wy;
    o.w = xv.w*wx + yv.w*wy;
    *(float4*)(orow + k) = o;
  }
}

extern "C" void kernel_launch(void* const* d_in, const int* in_sizes, int n_in,
                              void* d_out, int out_size, void* d_ws, size_t ws_size,
                              hipStream_t stream){
  const float* x  = (const float*)d_in[0];
  const float* y  = (const float*)d_in[1];
  const float* W1 = (const float*)d_in[2];
  const float* b1 = (const float*)d_in[3];
  const float* g1 = (const float*)d_in[4];
  const float* be1= (const float*)d_in[5];
  const float* W2 = (const float*)d_in[6];
  const float* b2 = (const float*)d_in[7];
  const float* g2 = (const float*)d_in[8];
  const float* be2= (const float*)d_in[9];
  const float* W3 = (const float*)d_in[10];
  const float* b3 = (const float*)d_in[11];
  const float* W4 = (const float*)d_in[12];
  const float* b4 = (const float*)d_in[13];
  const float* W5 = (const float*)d_in[14];
  const float* b5 = (const float*)d_in[15];
  float* out = (float*)d_out;

  // Layout (~118 MB, proven): [W1t][W2t][S0: xbf -> phiY][S2: ybf][S1: phiX][small]
  unsigned short* W1t = (unsigned short*)d_ws;
  unsigned short* W2t = W1t + CD*CD;
  unsigned short* S0  = W2t + CD*CD;                    // xbf, later phiY
  unsigned short* S2  = S0 + (size_t)MROWS*CD;          // ybf
  unsigned short* S1  = S2 + (size_t)MROWS*CD;          // phiX
  float* u3   = (float*)(S1 + (size_t)MROWS*CD);        // 768
  float* u4s  = u3 + CD;                                // 392
  float* cbuf = u4s + T2;                               // 1 (+pad)
  float* t    = cbuf + 4;                               // (128+1)*768

  prep_wt<<<dim3(12,12,2), 256, 0, stream>>>(W1, W2, W1t, W2t);
  prep_u<<<(CD + T2 + 4)/4, 256, 0, stream>>>(W3, W4, W5, b3, b4, b5, u3, u4s, cbuf);
  init_t<<<((NB+1)*CD + 255)/256, 256, 0, stream>>>(u3, t);

  cvt2<<<2048, 256, 0, stream>>>(x, y, S0);   // fills S0=xbf and S2=ybf (contiguous)

  phi_gemm<<<1176, 256, 0, stream>>>(S0, W1t, b1, g1, be1, u4s,      S1, t);  // phiX
  phi_gemm<<<1176, 256, 0, stream>>>(S2, W2t, b2, g2, be2, u4s + NT, S0, t);  // phiY over xbf

  comp_wout<<<MROWS/4, 256, 0, stream>>>(S1, S0, t, cbuf, x, y, out);
}